// Round 1
// baseline (279.493 us; speedup 1.0000x reference)
//
#include <hip/hip_runtime.h>
#include <hip/hip_bf16.h>

// Problem constants (from setup_inputs): B=2, Lq=4096, C=384, M=4 modalities,
// H=6 heads, P=4 points, Lv=1 level, 64x64 grid, Dh=64.
#define RTOT 8192      // B*Lq
#define C_   384
#define M_   4
#define H_   6
#define P_   4
#define KOUT 1536      // M_*C_  (concatenated attn for single out-GEMM)

typedef __bf16 bf16;
typedef bf16  bf16x8 __attribute__((ext_vector_type(8)));
typedef float f32x4  __attribute__((ext_vector_type(4)));

// ---------------------------------------------------------------------------
// Weight prep: bf16-convert + transpose to [N][K]; fold gamma into Wout;
// concat Woff|Waw into one padded [128][384] per modality; fused biases.
// ---------------------------------------------------------------------------
#define S0 589824    // WvT:    4*384*384
#define S1 786432    // +WoffawT: 4*128*384
#define S2 1376256   // +WoutT: 384*1536
#define S3 1376768   // +oabias: 4*128
#define S4 1377152   // +boutbig: 384

__global__ __launch_bounds__(256) void cvt_kernel(
    const float* __restrict__ Wv, const float* __restrict__ Woff,
    const float* __restrict__ Waw, const float* __restrict__ Wout,
    const float* __restrict__ gamma, const float* __restrict__ boff,
    const float* __restrict__ baw, const float* __restrict__ bout,
    bf16* __restrict__ WvT, bf16* __restrict__ WoffawT, bf16* __restrict__ WoutT,
    float* __restrict__ oabias, float* __restrict__ boutbig)
{
    for (int idx = blockIdx.x * 256 + threadIdx.x; idx < S4; idx += gridDim.x * 256) {
        if (idx < S0) {
            int t = idx; int m = t / (C_ * C_); int rr = t % (C_ * C_);
            int n = rr / C_, k = rr % C_;
            WvT[t] = (bf16)Wv[(size_t)m * C_ * C_ + (size_t)k * C_ + n];
        } else if (idx < S1) {
            int t = idx - S0; int m = t / (128 * C_); int rr = t % (128 * C_);
            int n = rr / C_, k = rr % C_;
            float v = 0.f;
            if (n < 48)      v = Woff[(size_t)m * C_ * 48 + (size_t)k * 48 + n];
            else if (n < 72) v = Waw[(size_t)m * C_ * 24 + (size_t)k * 24 + (n - 48)];
            WoffawT[t] = (bf16)v;
        } else if (idx < S2) {
            int t = idx - S1; int n = t / KOUT; int kk = t % KOUT;
            int m = kk / C_, k = kk % C_;
            WoutT[t] = (bf16)(Wout[(size_t)m * C_ * C_ + (size_t)k * C_ + n] * gamma[m * C_ + n]);
        } else if (idx < S3) {
            int t = idx - S2; int m = t / 128; int n = t % 128;
            float v = 0.f;
            if (n < 48)      v = boff[m * 48 + n];
            else if (n < 72) v = baw[m * 24 + (n - 48)];
            oabias[t] = v;
        } else {
            int c = idx - S3;
            float s = 0.f;
            for (int m = 0; m < M_; ++m) s += gamma[m * C_ + c] * bout[m * C_ + c];
            boutbig[c] = s;
        }
    }
}

// ---------------------------------------------------------------------------
// LayerNorm: one wave per row. which=0 -> query->qn, which=1..4 -> feats->fn.
// ---------------------------------------------------------------------------
__global__ __launch_bounds__(64) void ln_kernel(
    const float* __restrict__ query, const float* __restrict__ feat,
    const float* __restrict__ feat_other,
    const float* __restrict__ qn_g, const float* __restrict__ qn_b,
    const float* __restrict__ fn_g, const float* __restrict__ fn_b,
    bf16* __restrict__ qn, bf16* __restrict__ fn)
{
    const int r = blockIdx.x;
    const int which = blockIdx.y;
    const int lane = threadIdx.x;
    const float* src; const float* g; const float* bb; bf16* dst;
    if (which == 0) { src = query; g = qn_g; bb = qn_b; dst = qn; }
    else {
        int m = which - 1;
        src = (m == 0) ? feat : feat_other + (size_t)(m - 1) * RTOT * C_;
        g = fn_g + m * C_; bb = fn_b + m * C_; dst = fn + (size_t)m * RTOT * C_;
    }
    src += (size_t)r * C_; dst += (size_t)r * C_;
    float v[6]; float s = 0.f, sq = 0.f;
#pragma unroll
    for (int j = 0; j < 6; ++j) {
        v[j] = src[lane + j * 64];
        s += v[j]; sq += v[j] * v[j];
    }
#pragma unroll
    for (int o = 1; o < 64; o <<= 1) {
        s += __shfl_xor(s, o);
        sq += __shfl_xor(sq, o);
    }
    const float mean = s * (1.f / C_);
    const float var  = sq * (1.f / C_) - mean * mean;
    const float rs   = rsqrtf(var + 1e-6f);
#pragma unroll
    for (int j = 0; j < 6; ++j) {
        int c = lane + j * 64;
        dst[c] = (bf16)((v[j] - mean) * rs * g[c] + bb[c]);
    }
}

// ---------------------------------------------------------------------------
// bf16 MFMA GEMM: C[RxN] = A[RxK] @ W^T[N][K] + bias, batched over blockIdx.z.
// BM=128, BN=64, BK=32; 4 waves, each wave 32 rows x 64 cols (2x4 fragments).
// MODE 0: bf16 out. MODE 1: f32 out. MODE 2: f32 out + extra (query) add.
// ---------------------------------------------------------------------------
template <int MODE>
__global__ __launch_bounds__(256) void gemm_kernel(
    const bf16* __restrict__ A, long long aStride,
    const bf16* __restrict__ W, long long wStride,
    const float* __restrict__ bias, int biasStride,
    const float* __restrict__ extra,
    void* __restrict__ OutP, long long oStride,
    int K, int ldo)
{
    __shared__ bf16 As[128][40];   // +8 pad: 2-way-max bank aliasing
    __shared__ bf16 Bs[64][40];
    const int m = blockIdx.z;
    A += (long long)m * aStride;
    W += (long long)m * wStride;
    bias += m * biasStride;
    const int brow = blockIdx.x * 128;
    const int bcol = blockIdx.y * 64;
    const int tid = threadIdx.x;
    const int lane = tid & 63;
    const int wave = tid >> 6;
    const int lr = lane & 15, lg = lane >> 4;

    f32x4 acc[2][4] = {};

    for (int k0 = 0; k0 < K; k0 += 32) {
#pragma unroll
        for (int c = 0; c < 2; ++c) {
            int id = tid + c * 256;
            int row = id >> 2, ko = (id & 3) * 8;
            *reinterpret_cast<bf16x8*>(&As[row][ko]) =
                *reinterpret_cast<const bf16x8*>(A + (long long)(brow + row) * K + k0 + ko);
        }
        {
            int row = tid >> 2, ko = (tid & 3) * 8;
            *reinterpret_cast<bf16x8*>(&Bs[row][ko]) =
                *reinterpret_cast<const bf16x8*>(W + (long long)(bcol + row) * K + k0 + ko);
        }
        __syncthreads();
        bf16x8 af[2], bfr[4];
#pragma unroll
        for (int mi = 0; mi < 2; ++mi)
            af[mi] = *reinterpret_cast<const bf16x8*>(&As[wave * 32 + mi * 16 + lr][lg * 8]);
#pragma unroll
        for (int ni = 0; ni < 4; ++ni)
            bfr[ni] = *reinterpret_cast<const bf16x8*>(&Bs[ni * 16 + lr][lg * 8]);
#pragma unroll
        for (int mi = 0; mi < 2; ++mi)
#pragma unroll
            for (int ni = 0; ni < 4; ++ni)
                acc[mi][ni] = __builtin_amdgcn_mfma_f32_16x16x32_bf16(
                    af[mi], bfr[ni], acc[mi][ni], 0, 0, 0);
        __syncthreads();
    }

#pragma unroll
    for (int mi = 0; mi < 2; ++mi) {
#pragma unroll
        for (int ni = 0; ni < 4; ++ni) {
#pragma unroll
            for (int r = 0; r < 4; ++r) {
                int row = brow + wave * 32 + mi * 16 + lg * 4 + r;
                int col = bcol + ni * 16 + lr;
                float v = acc[mi][ni][r] + bias[col];
                long long o = (long long)m * oStride + (long long)row * ldo + col;
                if (MODE == 0)      ((bf16*)OutP)[o] = (bf16)v;
                else if (MODE == 1) ((float*)OutP)[o] = v;
                else                ((float*)OutP)[o] = v + extra[(long long)row * ldo + col];
            }
        }
    }
}

// ---------------------------------------------------------------------------
// Deformable sampling: block = (row, modality), wave = head, lane = channel.
// Reads off/aw from offaw[Rx128/m], softmax over 4 points, bilinear-gathers
// bf16 value, writes attn interleaved [R][M*384] for one fused out-GEMM.
// Corner-validity branches are wave-uniform (per (r,m,h,p)) -> no divergence.
// ---------------------------------------------------------------------------
__global__ __launch_bounds__(384) void sample_kernel(
    const float* __restrict__ offaw, const float* __restrict__ ref,
    const bf16* __restrict__ value, bf16* __restrict__ attn)
{
    const int r = blockIdx.x;
    const int m = blockIdx.y;
    const int h = threadIdx.x >> 6;
    const int d = threadIdx.x & 63;
    const int b = r >> 12;   // /4096
    const float* oa = offaw + ((long long)m * RTOT + r) * 128;
    const float rx = ref[r * 2 + 0] * 64.f - 0.5f;
    const float ry = ref[r * 2 + 1] * 64.f - 0.5f;

    float e[4]; float mx = -1e30f;
#pragma unroll
    for (int p = 0; p < 4; ++p) { e[p] = oa[48 + h * 4 + p]; mx = fmaxf(mx, e[p]); }
    float s = 0.f;
#pragma unroll
    for (int p = 0; p < 4; ++p) { e[p] = expf(e[p] - mx); s += e[p]; }
    const float inv = 1.f / s;

    const bf16* vb = value + ((long long)m * RTOT + (long long)b * 4096) * C_ + h * 64 + d;
    float acc = 0.f;
#pragma unroll
    for (int p = 0; p < 4; ++p) {
        float x = rx + oa[h * 8 + p * 2 + 0];
        float y = ry + oa[h * 8 + p * 2 + 1];
        float xf = floorf(x), yf = floorf(y);
        float wx = x - xf, wy = y - yf;
        int x0 = (int)xf, y0 = (int)yf;
        float v00 = 0.f, v01 = 0.f, v10 = 0.f, v11 = 0.f;
        bool xok0 = (x0 >= 0) && (x0 < 64);
        bool xok1 = (x0 + 1 >= 0) && (x0 + 1 < 64);
        bool yok0 = (y0 >= 0) && (y0 < 64);
        bool yok1 = (y0 + 1 >= 0) && (y0 + 1 < 64);
        if (yok0) {
            if (xok0) v00 = (float)vb[((long long)(y0 * 64 + x0)) * C_];
            if (xok1) v01 = (float)vb[((long long)(y0 * 64 + x0 + 1)) * C_];
        }
        if (yok1) {
            if (xok0) v10 = (float)vb[((long long)((y0 + 1) * 64 + x0)) * C_];
            if (xok1) v11 = (float)vb[((long long)((y0 + 1) * 64 + x0 + 1)) * C_];
        }
        float top = v00 + (v01 - v00) * wx;
        float bot = v10 + (v11 - v10) * wx;
        acc += (e[p] * inv) * (top + (bot - top) * wy);
    }
    attn[(long long)r * KOUT + m * C_ + h * 64 + d] = (bf16)acc;
}

// ---------------------------------------------------------------------------
extern "C" void kernel_launch(void* const* d_in, const int* in_sizes, int n_in,
                              void* d_out, int out_size, void* d_ws, size_t ws_size,
                              hipStream_t stream)
{
    const float* query      = (const float*)d_in[0];
    const float* ref        = (const float*)d_in[1];
    const float* feat       = (const float*)d_in[2];
    const float* feat_other = (const float*)d_in[3];
    const float* qn_g = (const float*)d_in[4];
    const float* qn_b = (const float*)d_in[5];
    const float* fn_g = (const float*)d_in[6];
    const float* fn_b = (const float*)d_in[7];
    const float* Wv   = (const float*)d_in[8];
    const float* bv   = (const float*)d_in[9];
    const float* Woff = (const float*)d_in[10];
    const float* boff = (const float*)d_in[11];
    const float* Waw  = (const float*)d_in[12];
    const float* baw  = (const float*)d_in[13];
    const float* Wout = (const float*)d_in[14];
    const float* bout = (const float*)d_in[15];
    const float* gamma = (const float*)d_in[16];
    float* out = (float*)d_out;

    // Workspace carve (all sizes 256B-aligned). Total ~101.3 MB.
    char* ws = (char*)d_ws;
    size_t off = 0;
    auto carve = [&](size_t bytes) { char* p = ws + off; off += (bytes + 255) & ~(size_t)255; return p; };
    bf16*  qn      = (bf16*)carve((size_t)RTOT * C_ * 2);
    bf16*  fn      = (bf16*)carve((size_t)M_ * RTOT * C_ * 2);
    bf16*  value   = (bf16*)carve((size_t)M_ * RTOT * C_ * 2);
    bf16*  attn    = (bf16*)carve((size_t)RTOT * KOUT * 2);
    float* offaw   = (float*)carve((size_t)M_ * RTOT * 128 * 4);
    bf16*  WvT     = (bf16*)carve((size_t)M_ * C_ * C_ * 2);
    bf16*  WoffawT = (bf16*)carve((size_t)M_ * 128 * C_ * 2);
    bf16*  WoutT   = (bf16*)carve((size_t)C_ * KOUT * 2);
    float* oabias  = (float*)carve((size_t)M_ * 128 * 4);
    float* boutbig = (float*)carve((size_t)C_ * 4);

    cvt_kernel<<<512, 256, 0, stream>>>(Wv, Woff, Waw, Wout, gamma, boff, baw, bout,
                                        WvT, WoffawT, WoutT, oabias, boutbig);
    ln_kernel<<<dim3(RTOT, 5), 64, 0, stream>>>(query, feat, feat_other,
                                                qn_g, qn_b, fn_g, fn_b, qn, fn);
    // value[m] = fn[m] @ Wv[m] + bv[m]   (bf16 out)
    gemm_kernel<0><<<dim3(RTOT / 128, C_ / 64, M_), 256, 0, stream>>>(
        fn, (long long)RTOT * C_, WvT, (long long)C_ * C_, bv, C_, nullptr,
        value, (long long)RTOT * C_, C_, C_);
    // offaw[m] = qn @ [Woff|Waw|pad][m] + bias   (f32 out, N padded to 128)
    gemm_kernel<1><<<dim3(RTOT / 128, 2, M_), 256, 0, stream>>>(
        qn, 0LL, WoffawT, (long long)128 * C_, oabias, 128, nullptr,
        offaw, (long long)RTOT * 128, C_, 128);
    // bilinear sampling + point-weighted sum -> attn [R][M*384] bf16
    sample_kernel<<<dim3(RTOT, M_), 384, 0, stream>>>(offaw, ref, value, attn);
    // out = query + attn_cat @ WoutT_big + (sum_m gamma*bout)   (K=1536)
    gemm_kernel<2><<<dim3(RTOT / 128, C_ / 64, 1), 256, 0, stream>>>(
        attn, 0LL, WoutT, 0LL, boutbig, 0, query,
        out, 0LL, KOUT, C_);
}

// Round 2
// 143.160 us; speedup vs baseline: 1.9523x; 1.9523x over previous
//
#include <hip/hip_runtime.h>
#include <hip/hip_bf16.h>

// Problem constants (from setup_inputs): B=2, Lq=4096, C=384, M=4 modalities,
// H=6 heads, P=4 points, Lv=1 level, 64x64 grid, Dh=64.
#define RTOT 8192      // B*Lq
#define C_   384
#define M_   4
#define H_   6
#define P_   4
#define KOUT 1536      // M_*C_  (concatenated attn for single out-GEMM)

typedef __bf16 bf16;
typedef bf16  bf16x8 __attribute__((ext_vector_type(8)));
typedef float f32x4  __attribute__((ext_vector_type(4)));

// ---------------------------------------------------------------------------
// Weight prep: bf16-convert + transpose to [N][K]; fold gamma into Wout;
// concat Woff|Waw into one padded [128][384] per modality; fused biases.
// ---------------------------------------------------------------------------
#define S0 589824    // WvT:    4*384*384
#define S1 786432    // +WoffawT: 4*128*384
#define S2 1376256   // +WoutT: 384*1536
#define S3 1376768   // +oabias: 4*128
#define S4 1377152   // +boutbig: 384

__global__ __launch_bounds__(256) void cvt_kernel(
    const float* __restrict__ Wv, const float* __restrict__ Woff,
    const float* __restrict__ Waw, const float* __restrict__ Wout,
    const float* __restrict__ gamma, const float* __restrict__ boff,
    const float* __restrict__ baw, const float* __restrict__ bout,
    bf16* __restrict__ WvT, bf16* __restrict__ WoffawT, bf16* __restrict__ WoutT,
    float* __restrict__ oabias, float* __restrict__ boutbig)
{
    for (int idx = blockIdx.x * 256 + threadIdx.x; idx < S4; idx += gridDim.x * 256) {
        if (idx < S0) {
            int t = idx; int m = t / (C_ * C_); int rr = t % (C_ * C_);
            int n = rr / C_, k = rr % C_;
            WvT[t] = (bf16)Wv[(size_t)m * C_ * C_ + (size_t)k * C_ + n];
        } else if (idx < S1) {
            int t = idx - S0; int m = t / (128 * C_); int rr = t % (128 * C_);
            int n = rr / C_, k = rr % C_;
            float v = 0.f;
            if (n < 48)      v = Woff[(size_t)m * C_ * 48 + (size_t)k * 48 + n];
            else if (n < 72) v = Waw[(size_t)m * C_ * 24 + (size_t)k * 24 + (n - 48)];
            WoffawT[t] = (bf16)v;
        } else if (idx < S2) {
            int t = idx - S1; int n = t / KOUT; int kk = t % KOUT;
            int m = kk / C_, k = kk % C_;
            WoutT[t] = (bf16)(Wout[(size_t)m * C_ * C_ + (size_t)k * C_ + n] * gamma[m * C_ + n]);
        } else if (idx < S3) {
            int t = idx - S2; int m = t / 128; int n = t % 128;
            float v = 0.f;
            if (n < 48)      v = boff[m * 48 + n];
            else if (n < 72) v = baw[m * 24 + (n - 48)];
            oabias[t] = v;
        } else {
            int c = idx - S3;
            float s = 0.f;
            for (int m = 0; m < M_; ++m) s += gamma[m * C_ + c] * bout[m * C_ + c];
            boutbig[c] = s;
        }
    }
}

// ---------------------------------------------------------------------------
// LayerNorm: 256 threads = 4 waves, one row per wave. blockIdx.y: 0 -> query,
// 1..4 -> feats.
// ---------------------------------------------------------------------------
__global__ __launch_bounds__(256) void ln_kernel(
    const float* __restrict__ query, const float* __restrict__ feat,
    const float* __restrict__ feat_other,
    const float* __restrict__ qn_g, const float* __restrict__ qn_b,
    const float* __restrict__ fn_g, const float* __restrict__ fn_b,
    bf16* __restrict__ qn, bf16* __restrict__ fn)
{
    const int r = blockIdx.x * 4 + (threadIdx.x >> 6);
    const int which = blockIdx.y;
    const int lane = threadIdx.x & 63;
    const float* src; const float* g; const float* bb; bf16* dst;
    if (which == 0) { src = query; g = qn_g; bb = qn_b; dst = qn; }
    else {
        int m = which - 1;
        src = (m == 0) ? feat : feat_other + (size_t)(m - 1) * RTOT * C_;
        g = fn_g + m * C_; bb = fn_b + m * C_; dst = fn + (size_t)m * RTOT * C_;
    }
    src += (size_t)r * C_; dst += (size_t)r * C_;
    float v[6]; float s = 0.f, sq = 0.f;
#pragma unroll
    for (int j = 0; j < 6; ++j) {
        v[j] = src[lane + j * 64];
        s += v[j]; sq += v[j] * v[j];
    }
#pragma unroll
    for (int o = 1; o < 64; o <<= 1) {
        s += __shfl_xor(s, o);
        sq += __shfl_xor(sq, o);
    }
    const float mean = s * (1.f / C_);
    const float var  = sq * (1.f / C_) - mean * mean;
    const float rs   = rsqrtf(var + 1e-6f);
#pragma unroll
    for (int j = 0; j < 6; ++j) {
        int c = lane + j * 64;
        dst[c] = (bf16)((v[j] - mean) * rs * g[c] + bb[c]);
    }
}

// ---------------------------------------------------------------------------
// bf16 MFMA GEMM: C[RxN] = A[RxK] @ W^T[N][K] + bias, batched over blockIdx.z.
// BM=128, BN=64, BK=32; 4 waves, each wave 32 rows x 64 cols (2x4 fragments).
// MODE 0: bf16 out. MODE 1: f32 out. MODE 2: f32 out + extra (query) add.
// ---------------------------------------------------------------------------
template <int MODE>
__global__ __launch_bounds__(256) void gemm_kernel(
    const bf16* __restrict__ A, long long aStride,
    const bf16* __restrict__ W, long long wStride,
    const float* __restrict__ bias, int biasStride,
    const float* __restrict__ extra,
    void* __restrict__ OutP, long long oStride,
    int K, int ldo)
{
    __shared__ bf16 As[128][40];   // +8 pad: 2-way-max bank aliasing
    __shared__ bf16 Bs[64][40];
    const int m = blockIdx.z;
    A += (long long)m * aStride;
    W += (long long)m * wStride;
    bias += m * biasStride;
    const int brow = blockIdx.x * 128;
    const int bcol = blockIdx.y * 64;
    const int tid = threadIdx.x;
    const int lane = tid & 63;
    const int wave = tid >> 6;
    const int lr = lane & 15, lg = lane >> 4;

    f32x4 acc[2][4] = {};

    for (int k0 = 0; k0 < K; k0 += 32) {
#pragma unroll
        for (int c = 0; c < 2; ++c) {
            int id = tid + c * 256;
            int row = id >> 2, ko = (id & 3) * 8;
            *reinterpret_cast<bf16x8*>(&As[row][ko]) =
                *reinterpret_cast<const bf16x8*>(A + (long long)(brow + row) * K + k0 + ko);
        }
        {
            int row = tid >> 2, ko = (tid & 3) * 8;
            *reinterpret_cast<bf16x8*>(&Bs[row][ko]) =
                *reinterpret_cast<const bf16x8*>(W + (long long)(bcol + row) * K + k0 + ko);
        }
        __syncthreads();
        bf16x8 af[2], bfr[4];
#pragma unroll
        for (int mi = 0; mi < 2; ++mi)
            af[mi] = *reinterpret_cast<const bf16x8*>(&As[wave * 32 + mi * 16 + lr][lg * 8]);
#pragma unroll
        for (int ni = 0; ni < 4; ++ni)
            bfr[ni] = *reinterpret_cast<const bf16x8*>(&Bs[ni * 16 + lr][lg * 8]);
#pragma unroll
        for (int mi = 0; mi < 2; ++mi)
#pragma unroll
            for (int ni = 0; ni < 4; ++ni)
                acc[mi][ni] = __builtin_amdgcn_mfma_f32_16x16x32_bf16(
                    af[mi], bfr[ni], acc[mi][ni], 0, 0, 0);
        __syncthreads();
    }

#pragma unroll
    for (int mi = 0; mi < 2; ++mi) {
#pragma unroll
        for (int ni = 0; ni < 4; ++ni) {
#pragma unroll
            for (int r = 0; r < 4; ++r) {
                int row = brow + wave * 32 + mi * 16 + lg * 4 + r;
                int col = bcol + ni * 16 + lr;
                float v = acc[mi][ni][r] + bias[col];
                long long o = (long long)m * oStride + (long long)row * ldo + col;
                if (MODE == 0)      ((bf16*)OutP)[o] = (bf16)v;
                else if (MODE == 1) ((float*)OutP)[o] = v;
                else                ((float*)OutP)[o] = v + extra[(long long)row * ldo + col];
            }
        }
    }
}

// ---------------------------------------------------------------------------
// Deformable sampling, phase-split:
//   Phase 1 (24 threads): per (h,p) softmax + bilinear coords -> 4 weights
//     (validity folded in, =0 for OOB corners) + 4 clamped indices, in LDS.
//   Phase 2 (384 threads = 6 waves, wave=h, lane=channel): 16 broadcast LDS
//     reads + 16 coalesced 128B gathers + 16 FMAs per lane.
// Grid is 1D, bid = local*8 + (m*2+b): consecutive block ids round-robin
// across the 8 XCDs, so each XCD touches exactly one (m,b) value slice
// (3.1 MB < 4 MB L2) -> value stays L2-resident per XCD.
// ---------------------------------------------------------------------------
__global__ __launch_bounds__(384) void sample_kernel(
    const float* __restrict__ offaw, const float* __restrict__ ref,
    const bf16* __restrict__ value, bf16* __restrict__ attn)
{
    const int bid   = blockIdx.x;
    const int combo = bid & 7;
    const int local = bid >> 3;         // r within batch, 0..4095
    const int m = combo >> 1, b = combo & 1;
    const int r = b * 4096 + local;

    __shared__ float w_s[24][4];
    __shared__ int   i_s[24][4];

    const int t = threadIdx.x;
    if (t < 24) {
        const int h = t >> 2, p = t & 3;
        const float* oa = offaw + ((long long)m * RTOT + r) * 128;
        // softmax over the 4 points of this head (lanes t^1, t^2 stay in-group)
        float e = oa[48 + h * 4 + p];
        float mx = e;
        mx = fmaxf(mx, __shfl_xor(mx, 1));
        mx = fmaxf(mx, __shfl_xor(mx, 2));
        float ex = expf(e - mx);
        float s = ex;
        s += __shfl_xor(s, 1);
        s += __shfl_xor(s, 2);
        const float aw = ex / s;
        // bilinear coords
        const float x = ref[r * 2 + 0] * 64.f - 0.5f + oa[h * 8 + p * 2 + 0];
        const float y = ref[r * 2 + 1] * 64.f - 0.5f + oa[h * 8 + p * 2 + 1];
        const float xf = floorf(x), yf = floorf(y);
        const float wx = x - xf, wy = y - yf;
        const int x0 = (int)xf, y0 = (int)yf;
        const bool xok0 = (x0 >= 0) && (x0 < 64);
        const bool xok1 = (x0 >= -1) && (x0 < 63);
        const bool yok0 = (y0 >= 0) && (y0 < 64);
        const bool yok1 = (y0 >= -1) && (y0 < 63);
        const int xc0 = min(max(x0, 0), 63),     xc1 = min(max(x0 + 1, 0), 63);
        const int yc0 = min(max(y0, 0), 63),     yc1 = min(max(y0 + 1, 0), 63);
        w_s[t][0] = aw * (1.f - wx) * (1.f - wy) * (float)(xok0 && yok0);
        w_s[t][1] = aw * wx         * (1.f - wy) * (float)(xok1 && yok0);
        w_s[t][2] = aw * (1.f - wx) * wy         * (float)(xok0 && yok1);
        w_s[t][3] = aw * wx         * wy         * (float)(xok1 && yok1);
        i_s[t][0] = yc0 * 64 + xc0;  i_s[t][1] = yc0 * 64 + xc1;
        i_s[t][2] = yc1 * 64 + xc0;  i_s[t][3] = yc1 * 64 + xc1;
    }
    __syncthreads();

    const int h = t >> 6, d = t & 63;
    const bf16* vb = value + ((long long)m * RTOT + (long long)b * 4096) * C_ + h * 64 + d;
    float acc = 0.f;
#pragma unroll
    for (int p = 0; p < 4; ++p) {
#pragma unroll
        for (int c = 0; c < 4; ++c) {
            const float w  = w_s[h * 4 + p][c];   // same-addr LDS broadcast
            const int   ix = i_s[h * 4 + p][c];
            acc += w * (float)vb[(long long)ix * C_];
        }
    }
    attn[(long long)r * KOUT + m * C_ + h * 64 + d] = (bf16)acc;
}

// ---------------------------------------------------------------------------
extern "C" void kernel_launch(void* const* d_in, const int* in_sizes, int n_in,
                              void* d_out, int out_size, void* d_ws, size_t ws_size,
                              hipStream_t stream)
{
    const float* query      = (const float*)d_in[0];
    const float* ref        = (const float*)d_in[1];
    const float* feat       = (const float*)d_in[2];
    const float* feat_other = (const float*)d_in[3];
    const float* qn_g = (const float*)d_in[4];
    const float* qn_b = (const float*)d_in[5];
    const float* fn_g = (const float*)d_in[6];
    const float* fn_b = (const float*)d_in[7];
    const float* Wv   = (const float*)d_in[8];
    const float* bv   = (const float*)d_in[9];
    const float* Woff = (const float*)d_in[10];
    const float* boff = (const float*)d_in[11];
    const float* Waw  = (const float*)d_in[12];
    const float* baw  = (const float*)d_in[13];
    const float* Wout = (const float*)d_in[14];
    const float* bout = (const float*)d_in[15];
    const float* gamma = (const float*)d_in[16];
    float* out = (float*)d_out;

    // Workspace carve (all sizes 256B-aligned). Total ~101.3 MB.
    char* ws = (char*)d_ws;
    size_t off = 0;
    auto carve = [&](size_t bytes) { char* p = ws + off; off += (bytes + 255) & ~(size_t)255; return p; };
    bf16*  qn      = (bf16*)carve((size_t)RTOT * C_ * 2);
    bf16*  fn      = (bf16*)carve((size_t)M_ * RTOT * C_ * 2);
    bf16*  value   = (bf16*)carve((size_t)M_ * RTOT * C_ * 2);
    bf16*  attn    = (bf16*)carve((size_t)RTOT * KOUT * 2);
    float* offaw   = (float*)carve((size_t)M_ * RTOT * 128 * 4);
    bf16*  WvT     = (bf16*)carve((size_t)M_ * C_ * C_ * 2);
    bf16*  WoffawT = (bf16*)carve((size_t)M_ * 128 * C_ * 2);
    bf16*  WoutT   = (bf16*)carve((size_t)C_ * KOUT * 2);
    float* oabias  = (float*)carve((size_t)M_ * 128 * 4);
    float* boutbig = (float*)carve((size_t)C_ * 4);

    cvt_kernel<<<512, 256, 0, stream>>>(Wv, Woff, Waw, Wout, gamma, boff, baw, bout,
                                        WvT, WoffawT, WoutT, oabias, boutbig);
    ln_kernel<<<dim3(RTOT / 4, 5), 256, 0, stream>>>(query, feat, feat_other,
                                                     qn_g, qn_b, fn_g, fn_b, qn, fn);
    // value[m] = fn[m] @ Wv[m] + bv[m]   (bf16 out)
    gemm_kernel<0><<<dim3(RTOT / 128, C_ / 64, M_), 256, 0, stream>>>(
        fn, (long long)RTOT * C_, WvT, (long long)C_ * C_, bv, C_, nullptr,
        value, (long long)RTOT * C_, C_, C_);
    // offaw[m] = qn @ [Woff|Waw|pad][m] + bias   (f32 out, N padded to 128)
    gemm_kernel<1><<<dim3(RTOT / 128, 2, M_), 256, 0, stream>>>(
        qn, 0LL, WoffawT, (long long)128 * C_, oabias, 128, nullptr,
        offaw, (long long)RTOT * 128, C_, 128);
    // bilinear sampling + point-weighted sum -> attn [R][M*384] bf16
    sample_kernel<<<dim3(RTOT * M_), 384, 0, stream>>>(offaw, ref, value, attn);
    // out = query + attn_cat @ WoutT_big + (sum_m gamma*bout)   (K=1536)
    gemm_kernel<2><<<dim3(RTOT / 128, C_ / 64, 1), 256, 0, stream>>>(
        attn, 0LL, WoutT, 0LL, boutbig, 0, query,
        out, 0LL, KOUT, C_);
}

// Round 3
// 131.296 us; speedup vs baseline: 2.1287x; 1.0904x over previous
//
#include <hip/hip_runtime.h>
#include <hip/hip_bf16.h>

// Problem constants: B=2, Lq=4096, C=384, M=4, H=6, P=4, Lv=1, 64x64, Dh=64.
#define RTOT 8192      // B*Lq
#define C_   384
#define M_   4
#define H_   6
#define P_   4
#define KOUT 1536      // M_*C_

typedef __bf16 bf16;
typedef bf16  bf16x8 __attribute__((ext_vector_type(8)));
typedef float f32x4  __attribute__((ext_vector_type(4)));

// async global->LDS, 16B per lane, linear LDS dest (wave-uniform base + lane*16)
#define GLOAD_LDS16(g, l) __builtin_amdgcn_global_load_lds( \
    (const __attribute__((address_space(1))) unsigned int*)(g), \
    (__attribute__((address_space(3))) unsigned int*)(l), 16, 0, 0)

// ---------------------------------------------------------------------------
// Weight prep: bf16 + transpose to [N][K]; fold gamma into Wout; concat
// Woff|Waw padded to [128][384]; fused biases.
// ---------------------------------------------------------------------------
#define S0 589824    // WvT:    4*384*384
#define S1 786432    // +WoffawT: 4*128*384
#define S2 1376256   // +WoutT: 384*1536
#define S3 1376768   // +oabias: 4*128
#define S4 1377152   // +boutbig: 384

__global__ __launch_bounds__(256) void cvt_kernel(
    const float* __restrict__ Wv, const float* __restrict__ Woff,
    const float* __restrict__ Waw, const float* __restrict__ Wout,
    const float* __restrict__ gamma, const float* __restrict__ boff,
    const float* __restrict__ baw, const float* __restrict__ bout,
    bf16* __restrict__ WvT, bf16* __restrict__ WoffawT, bf16* __restrict__ WoutT,
    float* __restrict__ oabias, float* __restrict__ boutbig)
{
    for (int idx = blockIdx.x * 256 + threadIdx.x; idx < S4; idx += gridDim.x * 256) {
        if (idx < S0) {
            int t = idx; int m = t / (C_ * C_); int rr = t % (C_ * C_);
            int n = rr / C_, k = rr % C_;
            WvT[t] = (bf16)Wv[(size_t)m * C_ * C_ + (size_t)k * C_ + n];
        } else if (idx < S1) {
            int t = idx - S0; int m = t / (128 * C_); int rr = t % (128 * C_);
            int n = rr / C_, k = rr % C_;
            float v = 0.f;
            if (n < 48)      v = Woff[(size_t)m * C_ * 48 + (size_t)k * 48 + n];
            else if (n < 72) v = Waw[(size_t)m * C_ * 24 + (size_t)k * 24 + (n - 48)];
            WoffawT[t] = (bf16)v;
        } else if (idx < S2) {
            int t = idx - S1; int n = t / KOUT; int kk = t % KOUT;
            int m = kk / C_, k = kk % C_;
            WoutT[t] = (bf16)(Wout[(size_t)m * C_ * C_ + (size_t)k * C_ + n] * gamma[m * C_ + n]);
        } else if (idx < S3) {
            int t = idx - S2; int m = t / 128; int n = t % 128;
            float v = 0.f;
            if (n < 48)      v = boff[m * 48 + n];
            else if (n < 72) v = baw[m * 24 + (n - 48)];
            oabias[t] = v;
        } else {
            int c = idx - S3;
            float s = 0.f;
            for (int m = 0; m < M_; ++m) s += gamma[m * C_ + c] * bout[m * C_ + c];
            boutbig[c] = s;
        }
    }
}

// ---------------------------------------------------------------------------
// LayerNorm: 256 threads = 4 waves, one row per wave.
// ---------------------------------------------------------------------------
__global__ __launch_bounds__(256) void ln_kernel(
    const float* __restrict__ query, const float* __restrict__ feat,
    const float* __restrict__ feat_other,
    const float* __restrict__ qn_g, const float* __restrict__ qn_b,
    const float* __restrict__ fn_g, const float* __restrict__ fn_b,
    bf16* __restrict__ qn, bf16* __restrict__ fn)
{
    const int r = blockIdx.x * 4 + (threadIdx.x >> 6);
    const int which = blockIdx.y;
    const int lane = threadIdx.x & 63;
    const float* src; const float* g; const float* bb; bf16* dst;
    if (which == 0) { src = query; g = qn_g; bb = qn_b; dst = qn; }
    else {
        int m = which - 1;
        src = (m == 0) ? feat : feat_other + (size_t)(m - 1) * RTOT * C_;
        g = fn_g + m * C_; bb = fn_b + m * C_; dst = fn + (size_t)m * RTOT * C_;
    }
    src += (size_t)r * C_; dst += (size_t)r * C_;
    float v[6]; float s = 0.f, sq = 0.f;
#pragma unroll
    for (int j = 0; j < 6; ++j) {
        v[j] = src[lane + j * 64];
        s += v[j]; sq += v[j] * v[j];
    }
#pragma unroll
    for (int o = 1; o < 64; o <<= 1) {
        s += __shfl_xor(s, o);
        sq += __shfl_xor(sq, o);
    }
    const float mean = s * (1.f / C_);
    const float var  = sq * (1.f / C_) - mean * mean;
    const float rs   = rsqrtf(var + 1e-6f);
#pragma unroll
    for (int j = 0; j < 6; ++j) {
        int c = lane + j * 64;
        dst[c] = (bf16)((v[j] - mean) * rs * g[c] + bb[c]);
    }
}

// ---------------------------------------------------------------------------
// bf16 MFMA GEMM, m97 structure: 128x128 tile, BK=32, 4 waves (2x2), 4x4
// fragments/wave, linear LDS, global_load_lds width-16 staging.
// MODE 0: bf16 out. MODE 1: f32 out. MODE 2: f32 out + extra add.
// ---------------------------------------------------------------------------
template <int MODE>
__global__ __launch_bounds__(256) void gemm_kernel(
    const bf16* __restrict__ A, long long aStride,
    const bf16* __restrict__ W, long long wStride,
    const float* __restrict__ bias, int biasStride,
    const float* __restrict__ extra,
    void* __restrict__ OutP, long long oStride,
    int K, int ldo)
{
    __shared__ __align__(16) bf16 As[128 * 32];
    __shared__ __align__(16) bf16 Bs[128 * 32];
    const int mb = blockIdx.z;
    A += (long long)mb * aStride;
    W += (long long)mb * wStride;
    bias += mb * biasStride;
    const int brow = blockIdx.x * 128;
    const int bcol = blockIdx.y * 128;
    const int tid = threadIdx.x;
    const int lane = tid & 63;
    const int wave = tid >> 6;
    const int wr = wave >> 1, wc = wave & 1;
    const int lr = lane & 15, lg = lane >> 4;

    f32x4 acc[4][4] = {};

    for (int k0 = 0; k0 < K; k0 += 32) {
#pragma unroll
        for (int c = 0; c < 2; ++c) {
            const int id = tid + c * 256;           // 0..511
            const int row = id >> 2, ko = (id & 3) * 8;
            GLOAD_LDS16(A + (long long)(brow + row) * K + k0 + ko, (char*)As + id * 16);
            GLOAD_LDS16(W + (long long)(bcol + row) * K + k0 + ko, (char*)Bs + id * 16);
        }
        __syncthreads();   // drains vmcnt before barrier (compiler-inserted)
        bf16x8 af[4], bfr[4];
#pragma unroll
        for (int mi = 0; mi < 4; ++mi)
            af[mi] = *reinterpret_cast<const bf16x8*>(&As[(wr * 64 + mi * 16 + lr) * 32 + lg * 8]);
#pragma unroll
        for (int ni = 0; ni < 4; ++ni)
            bfr[ni] = *reinterpret_cast<const bf16x8*>(&Bs[(wc * 64 + ni * 16 + lr) * 32 + lg * 8]);
#pragma unroll
        for (int mi = 0; mi < 4; ++mi)
#pragma unroll
            for (int ni = 0; ni < 4; ++ni)
                acc[mi][ni] = __builtin_amdgcn_mfma_f32_16x16x32_bf16(
                    af[mi], bfr[ni], acc[mi][ni], 0, 0, 0);
        __syncthreads();
    }

#pragma unroll
    for (int mi = 0; mi < 4; ++mi) {
#pragma unroll
        for (int ni = 0; ni < 4; ++ni) {
#pragma unroll
            for (int rr = 0; rr < 4; ++rr) {
                int row = brow + wr * 64 + mi * 16 + lg * 4 + rr;
                int col = bcol + wc * 64 + ni * 16 + lr;
                float v = acc[mi][ni][rr] + bias[col];
                long long o = (long long)mb * oStride + (long long)row * ldo + col;
                if (MODE == 0)      ((bf16*)OutP)[o] = (bf16)v;
                else if (MODE == 1) ((float*)OutP)[o] = v;
                else                ((float*)OutP)[o] = v + extra[(long long)row * ldo + col];
            }
        }
    }
}

// ---------------------------------------------------------------------------
// Deformable sampling. Block = 2 rows of one (m,b); 384 threads.
// Phase 1 (48 threads): per (row,h,p) softmax + bilinear -> 4 {weight,
//   byte-offset} pairs in LDS (validity folded, offsets premultiplied).
// Phase 2 (2 rows x 6 heads x 32 lanes): lane owns 2 channels. Read all 16
//   pairs (ds_read_b64), issue all 16 u32 gathers (full MLP), then 32 FMAs.
// Grid: bid&7 = m*2+b -> each XCD keeps one 3.1MB value slice L2-resident.
// ---------------------------------------------------------------------------
struct WP { float w; int off; };

__global__ __launch_bounds__(384) void sample_kernel(
    const float* __restrict__ offaw, const float* __restrict__ ref,
    const bf16* __restrict__ value, bf16* __restrict__ attn)
{
    const int bid   = blockIdx.x;
    const int combo = bid & 7;
    const int pair  = bid >> 3;          // 0..2047
    const int m = combo >> 1, b = combo & 1;
    const int r0 = b * 4096 + pair * 2;

    __shared__ WP wp_s[2][24][4];

    const int t = threadIdx.x;
    if (t < 48) {
        const int row = t / 24;
        const int i   = t % 24;          // h*4+p
        const int h = i >> 2, p = i & 3;
        const int r = r0 + row;
        const float* oa = offaw + ((long long)m * RTOT + r) * 128;
        float e = oa[48 + h * 4 + p];
        float mx = fmaxf(e, __shfl_xor(e, 1));
        mx = fmaxf(mx, __shfl_xor(mx, 2));
        float ex = expf(e - mx);
        float s = ex;
        s += __shfl_xor(s, 1);
        s += __shfl_xor(s, 2);
        const float aw = ex / s;
        const float x = ref[r * 2 + 0] * 64.f - 0.5f + oa[h * 8 + p * 2 + 0];
        const float y = ref[r * 2 + 1] * 64.f - 0.5f + oa[h * 8 + p * 2 + 1];
        const float xf = floorf(x), yf = floorf(y);
        const float wx = x - xf, wy = y - yf;
        const int x0 = (int)xf, y0 = (int)yf;
        const bool xok0 = (x0 >= 0) && (x0 < 64);
        const bool xok1 = (x0 >= -1) && (x0 < 63);
        const bool yok0 = (y0 >= 0) && (y0 < 64);
        const bool yok1 = (y0 >= -1) && (y0 < 63);
        const int xc0 = min(max(x0, 0), 63),     xc1 = min(max(x0 + 1, 0), 63);
        const int yc0 = min(max(y0, 0), 63),     yc1 = min(max(y0 + 1, 0), 63);
        WP w0 = { aw * (1.f - wx) * (1.f - wy) * (float)(xok0 && yok0), (yc0 * 64 + xc0) * (C_ * 2) };
        WP w1 = { aw * wx         * (1.f - wy) * (float)(xok1 && yok0), (yc0 * 64 + xc1) * (C_ * 2) };
        WP w2 = { aw * (1.f - wx) * wy         * (float)(xok0 && yok1), (yc1 * 64 + xc0) * (C_ * 2) };
        WP w3 = { aw * wx         * wy         * (float)(xok1 && yok1), (yc1 * 64 + xc1) * (C_ * 2) };
        wp_s[row][i][0] = w0;  wp_s[row][i][1] = w1;
        wp_s[row][i][2] = w2;  wp_s[row][i][3] = w3;
    }
    __syncthreads();

    const int row = t / 192;             // 0..1
    const int tl  = t % 192;
    const int h   = tl >> 5;             // 0..5
    const int l32 = tl & 31;             // channel pair
    const int r   = r0 + row;
    const char* vb = (const char*)(value
        + ((long long)m * RTOT + (long long)b * 4096) * C_ + h * 64 + l32 * 2);

    float wreg[16]; int oreg[16]; unsigned int vreg[16];
#pragma unroll
    for (int i = 0; i < 16; ++i) {
        WP wp = wp_s[row][h * 4 + (i >> 2)][i & 3];
        wreg[i] = wp.w; oreg[i] = wp.off;
    }
#pragma unroll
    for (int i = 0; i < 16; ++i)
        vreg[i] = *reinterpret_cast<const unsigned int*>(vb + oreg[i]);
    float acc0 = 0.f, acc1 = 0.f;
#pragma unroll
    for (int i = 0; i < 16; ++i) {
        unsigned int u = vreg[i];
        float lo = __builtin_bit_cast(float, u << 16);
        float hi = __builtin_bit_cast(float, u & 0xffff0000u);
        acc0 += wreg[i] * lo;
        acc1 += wreg[i] * hi;
    }
    union { bf16 h2[2]; unsigned int u; } o;
    o.h2[0] = (bf16)acc0; o.h2[1] = (bf16)acc1;
    *reinterpret_cast<unsigned int*>(attn + (long long)r * KOUT + m * C_ + h * 64 + l32 * 2) = o.u;
}

// ---------------------------------------------------------------------------
extern "C" void kernel_launch(void* const* d_in, const int* in_sizes, int n_in,
                              void* d_out, int out_size, void* d_ws, size_t ws_size,
                              hipStream_t stream)
{
    const float* query      = (const float*)d_in[0];
    const float* ref        = (const float*)d_in[1];
    const float* feat       = (const float*)d_in[2];
    const float* feat_other = (const float*)d_in[3];
    const float* qn_g = (const float*)d_in[4];
    const float* qn_b = (const float*)d_in[5];
    const float* fn_g = (const float*)d_in[6];
    const float* fn_b = (const float*)d_in[7];
    const float* Wv   = (const float*)d_in[8];
    const float* bv   = (const float*)d_in[9];
    const float* Woff = (const float*)d_in[10];
    const float* boff = (const float*)d_in[11];
    const float* Waw  = (const float*)d_in[12];
    const float* baw  = (const float*)d_in[13];
    const float* Wout = (const float*)d_in[14];
    const float* bout = (const float*)d_in[15];
    const float* gamma = (const float*)d_in[16];
    float* out = (float*)d_out;

    char* ws = (char*)d_ws;
    size_t off = 0;
    auto carve = [&](size_t bytes) { char* p = ws + off; off += (bytes + 255) & ~(size_t)255; return p; };
    bf16*  qn      = (bf16*)carve((size_t)RTOT * C_ * 2);
    bf16*  fn      = (bf16*)carve((size_t)M_ * RTOT * C_ * 2);
    bf16*  value   = (bf16*)carve((size_t)M_ * RTOT * C_ * 2);
    bf16*  attn    = (bf16*)carve((size_t)RTOT * KOUT * 2);
    float* offaw   = (float*)carve((size_t)M_ * RTOT * 128 * 4);
    bf16*  WvT     = (bf16*)carve((size_t)M_ * C_ * C_ * 2);
    bf16*  WoffawT = (bf16*)carve((size_t)M_ * 128 * C_ * 2);
    bf16*  WoutT   = (bf16*)carve((size_t)C_ * KOUT * 2);
    float* oabias  = (float*)carve((size_t)M_ * 128 * 4);
    float* boutbig = (float*)carve((size_t)C_ * 4);

    cvt_kernel<<<512, 256, 0, stream>>>(Wv, Woff, Waw, Wout, gamma, boff, baw, bout,
                                        WvT, WoffawT, WoutT, oabias, boutbig);
    ln_kernel<<<dim3(RTOT / 4, 5), 256, 0, stream>>>(query, feat, feat_other,
                                                     qn_g, qn_b, fn_g, fn_b, qn, fn);
    // value[m] = fn[m] @ WvT[m] + bv[m]   (bf16 out)
    gemm_kernel<0><<<dim3(RTOT / 128, C_ / 128, M_), 256, 0, stream>>>(
        fn, (long long)RTOT * C_, WvT, (long long)C_ * C_, bv, C_, nullptr,
        value, (long long)RTOT * C_, C_, C_);
    // offaw[m] = qn @ WoffawT[m] + oabias  (f32 out, N=128)
    gemm_kernel<1><<<dim3(RTOT / 128, 1, M_), 256, 0, stream>>>(
        qn, 0LL, WoffawT, (long long)128 * C_, oabias, 128, nullptr,
        offaw, (long long)RTOT * 128, C_, 128);
    // sampling -> attn [R][1536] bf16
    sample_kernel<<<dim3(RTOT * M_ / 2), 384, 0, stream>>>(offaw, ref, value, attn);
    // out = query + attn @ WoutT + boutbig  (K=1536)
    gemm_kernel<2><<<dim3(RTOT / 128, C_ / 128, 1), 256, 0, stream>>>(
        attn, 0LL, WoutT, 0LL, boutbig, 0, query,
        out, 0LL, KOUT, C_);
}

// Round 4
// 124.042 us; speedup vs baseline: 2.2532x; 1.0585x over previous
//
#include <hip/hip_runtime.h>
#include <hip/hip_bf16.h>

// Problem constants: B=2, Lq=4096, C=384, M=4, H=6, P=4, Lv=1, 64x64, Dh=64.
#define RTOT 8192      // B*Lq
#define C_   384
#define M_   4
#define H_   6
#define P_   4
#define KOUT 1536      // M_*C_

typedef __bf16 bf16;
typedef bf16  bf16x8 __attribute__((ext_vector_type(8)));
typedef float f32x4  __attribute__((ext_vector_type(4)));

// async global->LDS, 16B per lane, linear LDS dest (wave-uniform base + lane*16)
#define GLOAD_LDS16(g, l) __builtin_amdgcn_global_load_lds( \
    (const __attribute__((address_space(1))) unsigned int*)(g), \
    (__attribute__((address_space(3))) unsigned int*)(l), 16, 0, 0)

// ---------------------------------------------------------------------------
// Weight prep: bf16 + transpose to [N][K]; fold gamma into Wout; concat
// Woff|Waw padded to [128][384]; fused biases.
// ---------------------------------------------------------------------------
#define S0 589824    // WvT:    4*384*384
#define S1 786432    // +WoffawT: 4*128*384
#define S2 1376256   // +WoutT: 384*1536
#define S3 1376768   // +oabias: 4*128
#define S4 1377152   // +boutbig: 384

__global__ __launch_bounds__(256) void cvt_kernel(
    const float* __restrict__ Wv, const float* __restrict__ Woff,
    const float* __restrict__ Waw, const float* __restrict__ Wout,
    const float* __restrict__ gamma, const float* __restrict__ boff,
    const float* __restrict__ baw, const float* __restrict__ bout,
    bf16* __restrict__ WvT, bf16* __restrict__ WoffawT, bf16* __restrict__ WoutT,
    float* __restrict__ oabias, float* __restrict__ boutbig)
{
    for (int idx = blockIdx.x * 256 + threadIdx.x; idx < S4; idx += gridDim.x * 256) {
        if (idx < S0) {
            int t = idx; int m = t / (C_ * C_); int rr = t % (C_ * C_);
            int n = rr / C_, k = rr % C_;
            WvT[t] = (bf16)Wv[(size_t)m * C_ * C_ + (size_t)k * C_ + n];
        } else if (idx < S1) {
            int t = idx - S0; int m = t / (128 * C_); int rr = t % (128 * C_);
            int n = rr / C_, k = rr % C_;
            float v = 0.f;
            if (n < 48)      v = Woff[(size_t)m * C_ * 48 + (size_t)k * 48 + n];
            else if (n < 72) v = Waw[(size_t)m * C_ * 24 + (size_t)k * 24 + (n - 48)];
            WoffawT[t] = (bf16)v;
        } else if (idx < S2) {
            int t = idx - S1; int n = t / KOUT; int kk = t % KOUT;
            int m = kk / C_, k = kk % C_;
            WoutT[t] = (bf16)(Wout[(size_t)m * C_ * C_ + (size_t)k * C_ + n] * gamma[m * C_ + n]);
        } else if (idx < S3) {
            int t = idx - S2; int m = t / 128; int n = t % 128;
            float v = 0.f;
            if (n < 48)      v = boff[m * 48 + n];
            else if (n < 72) v = baw[m * 24 + (n - 48)];
            oabias[t] = v;
        } else {
            int c = idx - S3;
            float s = 0.f;
            for (int m = 0; m < M_; ++m) s += gamma[m * C_ + c] * bout[m * C_ + c];
            boutbig[c] = s;
        }
    }
}

// ---------------------------------------------------------------------------
// LayerNorm: 256 threads = 4 waves, one row per wave.
// ---------------------------------------------------------------------------
__global__ __launch_bounds__(256) void ln_kernel(
    const float* __restrict__ query, const float* __restrict__ feat,
    const float* __restrict__ feat_other,
    const float* __restrict__ qn_g, const float* __restrict__ qn_b,
    const float* __restrict__ fn_g, const float* __restrict__ fn_b,
    bf16* __restrict__ qn, bf16* __restrict__ fn)
{
    const int r = blockIdx.x * 4 + (threadIdx.x >> 6);
    const int which = blockIdx.y;
    const int lane = threadIdx.x & 63;
    const float* src; const float* g; const float* bb; bf16* dst;
    if (which == 0) { src = query; g = qn_g; bb = qn_b; dst = qn; }
    else {
        int m = which - 1;
        src = (m == 0) ? feat : feat_other + (size_t)(m - 1) * RTOT * C_;
        g = fn_g + m * C_; bb = fn_b + m * C_; dst = fn + (size_t)m * RTOT * C_;
    }
    src += (size_t)r * C_; dst += (size_t)r * C_;
    float v[6]; float s = 0.f, sq = 0.f;
#pragma unroll
    for (int j = 0; j < 6; ++j) {
        v[j] = src[lane + j * 64];
        s += v[j]; sq += v[j] * v[j];
    }
#pragma unroll
    for (int o = 1; o < 64; o <<= 1) {
        s += __shfl_xor(s, o);
        sq += __shfl_xor(sq, o);
    }
    const float mean = s * (1.f / C_);
    const float var  = sq * (1.f / C_) - mean * mean;
    const float rs   = rsqrtf(var + 1e-6f);
#pragma unroll
    for (int j = 0; j < 6; ++j) {
        int c = lane + j * 64;
        dst[c] = (bf16)((v[j] - mean) * rs * g[c] + bb[c]);
    }
}

// ---------------------------------------------------------------------------
// bf16 MFMA GEMM: 128x128 tile, BK=32, 4 waves (2x2), 4x4 frags/wave.
// Double-buffered LDS: next tile's global_load_lds issued BEFORE current
// tile's compute; single __syncthreads (auto vmcnt-drain) per K-step.
// Bank-conflict fix (rule 21, both-sides swizzle): within each 64B LDS row,
// 16B slot s holds global col-chunk s ^ ((row>>1)&3); ds_read uses the same
// XOR -> 16 lanes spread over 8 bank groups (2-way = free).
// MODE 0: bf16 out. MODE 1: f32 out. MODE 2: f32 out + extra add.
// ---------------------------------------------------------------------------
template <int MODE>
__global__ __launch_bounds__(256) void gemm_kernel(
    const bf16* __restrict__ A, long long aStride,
    const bf16* __restrict__ W, long long wStride,
    const float* __restrict__ bias, int biasStride,
    const float* __restrict__ extra,
    void* __restrict__ OutP, long long oStride,
    int K, int ldo)
{
    __shared__ __align__(16) bf16 As[2][128 * 32];
    __shared__ __align__(16) bf16 Bs[2][128 * 32];
    const int mb = blockIdx.z;
    A += (long long)mb * aStride;
    W += (long long)mb * wStride;
    bias += mb * biasStride;
    const int brow = blockIdx.x * 128;
    const int bcol = blockIdx.y * 128;
    const int tid = threadIdx.x;
    const int lane = tid & 63;
    const int wave = tid >> 6;
    const int wr = wave >> 1, wc = wave & 1;
    const int lr = lane & 15, lg = lane >> 4;

    // staging source offsets (pre-swizzled global columns)
    const int r0 = tid >> 2, s0 = tid & 3;
    const int r1 = r0 + 64;
    const long long aoff0 = (long long)(brow + r0) * K + (s0 ^ ((r0 >> 1) & 3)) * 8;
    const long long aoff1 = (long long)(brow + r1) * K + (s0 ^ ((r1 >> 1) & 3)) * 8;
    const long long boff0 = (long long)(bcol + r0) * K + (s0 ^ ((r0 >> 1) & 3)) * 8;
    const long long boff1 = (long long)(bcol + r1) * K + (s0 ^ ((r1 >> 1) & 3)) * 8;

    // fragment ds_read byte offsets (swizzled, loop-invariant)
    int aRd[4], bRd[4];
#pragma unroll
    for (int i = 0; i < 4; ++i) {
        const int ra = wr * 64 + i * 16 + lr;
        const int rb = wc * 64 + i * 16 + lr;
        aRd[i] = ra * 32 + (lg ^ ((ra >> 1) & 3)) * 8;
        bRd[i] = rb * 32 + (lg ^ ((rb >> 1) & 3)) * 8;
    }

    f32x4 acc[4][4] = {};

    // prologue: stage tile 0
    GLOAD_LDS16(A + aoff0, (char*)&As[0][0] + tid * 16);
    GLOAD_LDS16(A + aoff1, (char*)&As[0][0] + (tid + 256) * 16);
    GLOAD_LDS16(W + boff0, (char*)&Bs[0][0] + tid * 16);
    GLOAD_LDS16(W + boff1, (char*)&Bs[0][0] + (tid + 256) * 16);
    __syncthreads();

    int cur = 0;
    for (int k0 = 0; k0 < K; k0 += 32) {
        if (k0 + 32 < K) {   // issue next tile's loads before computing current
            const int nb = cur ^ 1;
            GLOAD_LDS16(A + aoff0 + k0 + 32, (char*)&As[nb][0] + tid * 16);
            GLOAD_LDS16(A + aoff1 + k0 + 32, (char*)&As[nb][0] + (tid + 256) * 16);
            GLOAD_LDS16(W + boff0 + k0 + 32, (char*)&Bs[nb][0] + tid * 16);
            GLOAD_LDS16(W + boff1 + k0 + 32, (char*)&Bs[nb][0] + (tid + 256) * 16);
        }
        bf16x8 af[4], bfr[4];
#pragma unroll
        for (int mi = 0; mi < 4; ++mi)
            af[mi] = *reinterpret_cast<const bf16x8*>(&As[cur][aRd[mi]]);
#pragma unroll
        for (int ni = 0; ni < 4; ++ni)
            bfr[ni] = *reinterpret_cast<const bf16x8*>(&Bs[cur][bRd[ni]]);
#pragma unroll
        for (int mi = 0; mi < 4; ++mi)
#pragma unroll
            for (int ni = 0; ni < 4; ++ni)
                acc[mi][ni] = __builtin_amdgcn_mfma_f32_16x16x32_bf16(
                    af[mi], bfr[ni], acc[mi][ni], 0, 0, 0);
        __syncthreads();   // drains vmcnt (next tile) + guards buffer reuse
        cur ^= 1;
    }

#pragma unroll
    for (int mi = 0; mi < 4; ++mi) {
#pragma unroll
        for (int ni = 0; ni < 4; ++ni) {
#pragma unroll
            for (int rr = 0; rr < 4; ++rr) {
                int row = brow + wr * 64 + mi * 16 + lg * 4 + rr;
                int col = bcol + wc * 64 + ni * 16 + lr;
                float v = acc[mi][ni][rr] + bias[col];
                long long o = (long long)mb * oStride + (long long)row * ldo + col;
                if (MODE == 0)      ((bf16*)OutP)[o] = (bf16)v;
                else if (MODE == 1) ((float*)OutP)[o] = v;
                else                ((float*)OutP)[o] = v + extra[(long long)row * ldo + col];
            }
        }
    }
}

// ---------------------------------------------------------------------------
// Deformable sampling. Block = 2 rows of one (m,b); 384 threads.
// Phase 1 (48 threads): per (row,h,p) softmax + bilinear -> 4 {weight,
//   byte-offset} pairs in LDS (validity folded, offsets premultiplied).
// Phase 2 (2 rows x 6 heads x 32 lanes): lane owns 2 channels, 16 u32 gathers
//   issued back-to-back (MLP), then 32 FMAs.
// Grid: bid&7 = m*2+b -> each XCD keeps one 3.1MB value slice L2-resident.
// ---------------------------------------------------------------------------
struct WP { float w; int off; };

__global__ __launch_bounds__(384) void sample_kernel(
    const float* __restrict__ offaw, const float* __restrict__ ref,
    const bf16* __restrict__ value, bf16* __restrict__ attn)
{
    const int bid   = blockIdx.x;
    const int combo = bid & 7;
    const int pair  = bid >> 3;          // 0..2047
    const int m = combo >> 1, b = combo & 1;
    const int r0 = b * 4096 + pair * 2;

    __shared__ WP wp_s[2][24][4];

    const int t = threadIdx.x;
    if (t < 48) {
        const int row = t / 24;
        const int i   = t % 24;          // h*4+p
        const int h = i >> 2, p = i & 3;
        const int r = r0 + row;
        const float* oa = offaw + ((long long)m * RTOT + r) * 128;
        float e = oa[48 + h * 4 + p];
        float mx = fmaxf(e, __shfl_xor(e, 1));
        mx = fmaxf(mx, __shfl_xor(mx, 2));
        float ex = expf(e - mx);
        float s = ex;
        s += __shfl_xor(s, 1);
        s += __shfl_xor(s, 2);
        const float aw = ex / s;
        const float x = ref[r * 2 + 0] * 64.f - 0.5f + oa[h * 8 + p * 2 + 0];
        const float y = ref[r * 2 + 1] * 64.f - 0.5f + oa[h * 8 + p * 2 + 1];
        const float xf = floorf(x), yf = floorf(y);
        const float wx = x - xf, wy = y - yf;
        const int x0 = (int)xf, y0 = (int)yf;
        const bool xok0 = (x0 >= 0) && (x0 < 64);
        const bool xok1 = (x0 >= -1) && (x0 < 63);
        const bool yok0 = (y0 >= 0) && (y0 < 64);
        const bool yok1 = (y0 >= -1) && (y0 < 63);
        const int xc0 = min(max(x0, 0), 63),     xc1 = min(max(x0 + 1, 0), 63);
        const int yc0 = min(max(y0, 0), 63),     yc1 = min(max(y0 + 1, 0), 63);
        WP w0 = { aw * (1.f - wx) * (1.f - wy) * (float)(xok0 && yok0), (yc0 * 64 + xc0) * (C_ * 2) };
        WP w1 = { aw * wx         * (1.f - wy) * (float)(xok1 && yok0), (yc0 * 64 + xc1) * (C_ * 2) };
        WP w2 = { aw * (1.f - wx) * wy         * (float)(xok0 && yok1), (yc1 * 64 + xc0) * (C_ * 2) };
        WP w3 = { aw * wx         * wy         * (float)(xok1 && yok1), (yc1 * 64 + xc1) * (C_ * 2) };
        wp_s[row][i][0] = w0;  wp_s[row][i][1] = w1;
        wp_s[row][i][2] = w2;  wp_s[row][i][3] = w3;
    }
    __syncthreads();

    const int row = t / 192;             // 0..1
    const int tl  = t % 192;
    const int h   = tl >> 5;             // 0..5
    const int l32 = tl & 31;             // channel pair
    const int r   = r0 + row;
    const char* vb = (const char*)(value
        + ((long long)m * RTOT + (long long)b * 4096) * C_ + h * 64 + l32 * 2);

    float wreg[16]; int oreg[16]; unsigned int vreg[16];
#pragma unroll
    for (int i = 0; i < 16; ++i) {
        WP wp = wp_s[row][h * 4 + (i >> 2)][i & 3];
        wreg[i] = wp.w; oreg[i] = wp.off;
    }
#pragma unroll
    for (int i = 0; i < 16; ++i)
        vreg[i] = *reinterpret_cast<const unsigned int*>(vb + oreg[i]);
    float acc0 = 0.f, acc1 = 0.f;
#pragma unroll
    for (int i = 0; i < 16; ++i) {
        unsigned int u = vreg[i];
        float lo = __builtin_bit_cast(float, u << 16);
        float hi = __builtin_bit_cast(float, u & 0xffff0000u);
        acc0 += wreg[i] * lo;
        acc1 += wreg[i] * hi;
    }
    union { bf16 h2[2]; unsigned int u; } o;
    o.h2[0] = (bf16)acc0; o.h2[1] = (bf16)acc1;
    *reinterpret_cast<unsigned int*>(attn + (long long)r * KOUT + m * C_ + h * 64 + l32 * 2) = o.u;
}

// ---------------------------------------------------------------------------
extern "C" void kernel_launch(void* const* d_in, const int* in_sizes, int n_in,
                              void* d_out, int out_size, void* d_ws, size_t ws_size,
                              hipStream_t stream)
{
    const float* query      = (const float*)d_in[0];
    const float* ref        = (const float*)d_in[1];
    const float* feat       = (const float*)d_in[2];
    const float* feat_other = (const float*)d_in[3];
    const float* qn_g = (const float*)d_in[4];
    const float* qn_b = (const float*)d_in[5];
    const float* fn_g = (const float*)d_in[6];
    const float* fn_b = (const float*)d_in[7];
    const float* Wv   = (const float*)d_in[8];
    const float* bv   = (const float*)d_in[9];
    const float* Woff = (const float*)d_in[10];
    const float* boff = (const float*)d_in[11];
    const float* Waw  = (const float*)d_in[12];
    const float* baw  = (const float*)d_in[13];
    const float* Wout = (const float*)d_in[14];
    const float* bout = (const float*)d_in[15];
    const float* gamma = (const float*)d_in[16];
    float* out = (float*)d_out;

    char* ws = (char*)d_ws;
    size_t off = 0;
    auto carve = [&](size_t bytes) { char* p = ws + off; off += (bytes + 255) & ~(size_t)255; return p; };
    bf16*  qn      = (bf16*)carve((size_t)RTOT * C_ * 2);
    bf16*  fn      = (bf16*)carve((size_t)M_ * RTOT * C_ * 2);
    bf16*  value   = (bf16*)carve((size_t)M_ * RTOT * C_ * 2);
    bf16*  attn    = (bf16*)carve((size_t)RTOT * KOUT * 2);
    float* offaw   = (float*)carve((size_t)M_ * RTOT * 128 * 4);
    bf16*  WvT     = (bf16*)carve((size_t)M_ * C_ * C_ * 2);
    bf16*  WoffawT = (bf16*)carve((size_t)M_ * 128 * C_ * 2);
    bf16*  WoutT   = (bf16*)carve((size_t)C_ * KOUT * 2);
    float* oabias  = (float*)carve((size_t)M_ * 128 * 4);
    float* boutbig = (float*)carve((size_t)C_ * 4);

    cvt_kernel<<<512, 256, 0, stream>>>(Wv, Woff, Waw, Wout, gamma, boff, baw, bout,
                                        WvT, WoffawT, WoutT, oabias, boutbig);
    ln_kernel<<<dim3(RTOT / 4, 5), 256, 0, stream>>>(query, feat, feat_other,
                                                     qn_g, qn_b, fn_g, fn_b, qn, fn);
    // value[m] = fn[m] @ WvT[m] + bv[m]   (bf16 out)
    gemm_kernel<0><<<dim3(RTOT / 128, C_ / 128, M_), 256, 0, stream>>>(
        fn, (long long)RTOT * C_, WvT, (long long)C_ * C_, bv, C_, nullptr,
        value, (long long)RTOT * C_, C_, C_);
    // offaw[m] = qn @ WoffawT[m] + oabias  (f32 out, N=128)
    gemm_kernel<1><<<dim3(RTOT / 128, 1, M_), 256, 0, stream>>>(
        qn, 0LL, WoffawT, (long long)128 * C_, oabias, 128, nullptr,
        offaw, (long long)RTOT * 128, C_, 128);
    // sampling -> attn [R][1536] bf16
    sample_kernel<<<dim3(RTOT * M_ / 2), 384, 0, stream>>>(offaw, ref, value, attn);
    // out = query + attn @ WoutT + boutbig  (K=1536)
    gemm_kernel<2><<<dim3(RTOT / 128, C_ / 128, 1), 256, 0, stream>>>(
        attn, 0LL, WoutT, 0LL, boutbig, 0, query,
        out, 0LL, KOUT, C_);
}

// Round 5
// 120.089 us; speedup vs baseline: 2.3274x; 1.0329x over previous
//
#include <hip/hip_runtime.h>
#include <hip/hip_bf16.h>

// Problem constants: B=2, Lq=4096, C=384, M=4, H=6, P=4, Lv=1, 64x64, Dh=64.
#define RTOT 8192      // B*Lq
#define C_   384
#define M_   4
#define H_   6
#define P_   4
#define KOUT 1536      // M_*C_

typedef __bf16 bf16;
typedef bf16  bf16x8 __attribute__((ext_vector_type(8)));
typedef float f32x4  __attribute__((ext_vector_type(4)));

// async global->LDS, 16B per lane, linear LDS dest (wave-uniform base + lane*16)
#define GLOAD_LDS16(g, l) __builtin_amdgcn_global_load_lds( \
    (const __attribute__((address_space(1))) unsigned int*)(g), \
    (__attribute__((address_space(3))) unsigned int*)(l), 16, 0, 0)

// ---------------------------------------------------------------------------
// Weight prep: bf16 + transpose to [N][K]; fold gamma into Wout; concat
// Woff|Waw padded to [128][384]; fused biases.
// ---------------------------------------------------------------------------
#define S0 589824    // WvT:    4*384*384
#define S1 786432    // +WoffawT: 4*128*384
#define S2 1376256   // +WoutT: 384*1536
#define S3 1376768   // +oabias: 4*128
#define S4 1377152   // +boutbig: 384

__global__ __launch_bounds__(256) void cvt_kernel(
    const float* __restrict__ Wv, const float* __restrict__ Woff,
    const float* __restrict__ Waw, const float* __restrict__ Wout,
    const float* __restrict__ gamma, const float* __restrict__ boff,
    const float* __restrict__ baw, const float* __restrict__ bout,
    bf16* __restrict__ WvT, bf16* __restrict__ WoffawT, bf16* __restrict__ WoutT,
    float* __restrict__ oabias, float* __restrict__ boutbig)
{
    for (int idx = blockIdx.x * 256 + threadIdx.x; idx < S4; idx += gridDim.x * 256) {
        if (idx < S0) {
            int t = idx; int m = t / (C_ * C_); int rr = t % (C_ * C_);
            int n = rr / C_, k = rr % C_;
            WvT[t] = (bf16)Wv[(size_t)m * C_ * C_ + (size_t)k * C_ + n];
        } else if (idx < S1) {
            int t = idx - S0; int m = t / (128 * C_); int rr = t % (128 * C_);
            int n = rr / C_, k = rr % C_;
            float v = 0.f;
            if (n < 48)      v = Woff[(size_t)m * C_ * 48 + (size_t)k * 48 + n];
            else if (n < 72) v = Waw[(size_t)m * C_ * 24 + (size_t)k * 24 + (n - 48)];
            WoffawT[t] = (bf16)v;
        } else if (idx < S2) {
            int t = idx - S1; int n = t / KOUT; int kk = t % KOUT;
            int m = kk / C_, k = kk % C_;
            WoutT[t] = (bf16)(Wout[(size_t)m * C_ * C_ + (size_t)k * C_ + n] * gamma[m * C_ + n]);
        } else if (idx < S3) {
            int t = idx - S2; int m = t / 128; int n = t % 128;
            float v = 0.f;
            if (n < 48)      v = boff[m * 48 + n];
            else if (n < 72) v = baw[m * 24 + (n - 48)];
            oabias[t] = v;
        } else {
            int c = idx - S3;
            float s = 0.f;
            for (int m = 0; m < M_; ++m) s += gamma[m * C_ + c] * bout[m * C_ + c];
            boutbig[c] = s;
        }
    }
}

// ---------------------------------------------------------------------------
// LayerNorm: 256 threads = 4 waves, one row per wave.
// ---------------------------------------------------------------------------
__global__ __launch_bounds__(256) void ln_kernel(
    const float* __restrict__ query, const float* __restrict__ feat,
    const float* __restrict__ feat_other,
    const float* __restrict__ qn_g, const float* __restrict__ qn_b,
    const float* __restrict__ fn_g, const float* __restrict__ fn_b,
    bf16* __restrict__ qn, bf16* __restrict__ fn)
{
    const int r = blockIdx.x * 4 + (threadIdx.x >> 6);
    const int which = blockIdx.y;
    const int lane = threadIdx.x & 63;
    const float* src; const float* g; const float* bb; bf16* dst;
    if (which == 0) { src = query; g = qn_g; bb = qn_b; dst = qn; }
    else {
        int m = which - 1;
        src = (m == 0) ? feat : feat_other + (size_t)(m - 1) * RTOT * C_;
        g = fn_g + m * C_; bb = fn_b + m * C_; dst = fn + (size_t)m * RTOT * C_;
    }
    src += (size_t)r * C_; dst += (size_t)r * C_;
    float v[6]; float s = 0.f, sq = 0.f;
#pragma unroll
    for (int j = 0; j < 6; ++j) {
        v[j] = src[lane + j * 64];
        s += v[j]; sq += v[j] * v[j];
    }
#pragma unroll
    for (int o = 1; o < 64; o <<= 1) {
        s += __shfl_xor(s, o);
        sq += __shfl_xor(sq, o);
    }
    const float mean = s * (1.f / C_);
    const float var  = sq * (1.f / C_) - mean * mean;
    const float rs   = rsqrtf(var + 1e-6f);
#pragma unroll
    for (int j = 0; j < 6; ++j) {
        int c = lane + j * 64;
        dst[c] = (bf16)((v[j] - mean) * rs * g[c] + bb[c]);
    }
}

// ---------------------------------------------------------------------------
// bf16 MFMA GEMM: 64x64 tile (occupancy-first), BK=32, 4 waves (2x2), each
// wave 2x2 16x16 frags. Double-buffered LDS: next tile's global_load_lds
// issued before current tile's compute; one __syncthreads per K-step.
// Both-sides swizzle (rule 21): 16B slot s of LDS row holds global col-chunk
// s ^ ((row>>1)&3); ds_read applies the same XOR.
// MODE 0: bf16 out. MODE 1: f32 out. MODE 2: f32 out + extra add.
// ---------------------------------------------------------------------------
template <int MODE>
__global__ __launch_bounds__(256) void gemm_kernel(
    const bf16* __restrict__ A, long long aStride,
    const bf16* __restrict__ W, long long wStride,
    const float* __restrict__ bias, int biasStride,
    const float* __restrict__ extra,
    void* __restrict__ OutP, long long oStride,
    int K, int ldo)
{
    __shared__ __align__(16) bf16 As[2][64 * 32];
    __shared__ __align__(16) bf16 Bs[2][64 * 32];
    const int mb = blockIdx.z;
    A += (long long)mb * aStride;
    W += (long long)mb * wStride;
    bias += mb * biasStride;
    const int brow = blockIdx.x * 64;
    const int bcol = blockIdx.y * 64;
    const int tid = threadIdx.x;
    const int lane = tid & 63;
    const int wave = tid >> 6;
    const int wr = wave >> 1, wc = wave & 1;
    const int lr = lane & 15, lg = lane >> 4;

    // staging source offsets (pre-swizzled global columns); 1 load each for A,B
    const int r0 = tid >> 2, s0 = tid & 3;
    const long long aoff = (long long)(brow + r0) * K + (s0 ^ ((r0 >> 1) & 3)) * 8;
    const long long boff = (long long)(bcol + r0) * K + (s0 ^ ((r0 >> 1) & 3)) * 8;

    // fragment ds_read element offsets (swizzled, loop-invariant)
    int aRd[2], bRd[2];
#pragma unroll
    for (int i = 0; i < 2; ++i) {
        const int ra = wr * 32 + i * 16 + lr;
        const int rb = wc * 32 + i * 16 + lr;
        aRd[i] = ra * 32 + (lg ^ ((ra >> 1) & 3)) * 8;
        bRd[i] = rb * 32 + (lg ^ ((rb >> 1) & 3)) * 8;
    }

    f32x4 acc[2][2] = {};

    // prologue: stage tile 0
    GLOAD_LDS16(A + aoff, (char*)&As[0][0] + tid * 16);
    GLOAD_LDS16(W + boff, (char*)&Bs[0][0] + tid * 16);
    __syncthreads();

    int cur = 0;
    for (int k0 = 0; k0 < K; k0 += 32) {
        if (k0 + 32 < K) {   // issue next tile's loads before computing current
            const int nb = cur ^ 1;
            GLOAD_LDS16(A + aoff + k0 + 32, (char*)&As[nb][0] + tid * 16);
            GLOAD_LDS16(W + boff + k0 + 32, (char*)&Bs[nb][0] + tid * 16);
        }
        bf16x8 af[2], bfr[2];
#pragma unroll
        for (int mi = 0; mi < 2; ++mi)
            af[mi] = *reinterpret_cast<const bf16x8*>(&As[cur][aRd[mi]]);
#pragma unroll
        for (int ni = 0; ni < 2; ++ni)
            bfr[ni] = *reinterpret_cast<const bf16x8*>(&Bs[cur][bRd[ni]]);
#pragma unroll
        for (int mi = 0; mi < 2; ++mi)
#pragma unroll
            for (int ni = 0; ni < 2; ++ni)
                acc[mi][ni] = __builtin_amdgcn_mfma_f32_16x16x32_bf16(
                    af[mi], bfr[ni], acc[mi][ni], 0, 0, 0);
        __syncthreads();   // drains vmcnt (next tile) + guards buffer reuse
        cur ^= 1;
    }

#pragma unroll
    for (int mi = 0; mi < 2; ++mi) {
#pragma unroll
        for (int ni = 0; ni < 2; ++ni) {
#pragma unroll
            for (int rr = 0; rr < 4; ++rr) {
                int row = brow + wr * 32 + mi * 16 + lg * 4 + rr;
                int col = bcol + wc * 32 + ni * 16 + lr;
                float v = acc[mi][ni][rr] + bias[col];
                long long o = (long long)mb * oStride + (long long)row * ldo + col;
                if (MODE == 0)      ((bf16*)OutP)[o] = (bf16)v;
                else if (MODE == 1) ((float*)OutP)[o] = v;
                else                ((float*)OutP)[o] = v + extra[(long long)row * ldo + col];
            }
        }
    }
}

// ---------------------------------------------------------------------------
// Deformable sampling. Block = 2 rows of one (m,b); 384 threads.
// Phase 1 (48 threads): per (row,h,p) softmax + bilinear -> 4 {weight,
//   byte-offset} pairs in LDS (validity folded, offsets premultiplied).
// Phase 2 (2 rows x 6 heads x 32 lanes): lane owns 2 channels, 16 u32 gathers
//   issued back-to-back (MLP), then 32 FMAs.
// Grid: bid&7 = m*2+b -> each XCD keeps one 3.1MB value slice L2-resident.
// ---------------------------------------------------------------------------
struct WP { float w; int off; };

__global__ __launch_bounds__(384) void sample_kernel(
    const float* __restrict__ offaw, const float* __restrict__ ref,
    const bf16* __restrict__ value, bf16* __restrict__ attn)
{
    const int bid   = blockIdx.x;
    const int combo = bid & 7;
    const int pair  = bid >> 3;          // 0..2047
    const int m = combo >> 1, b = combo & 1;
    const int r0 = b * 4096 + pair * 2;

    __shared__ WP wp_s[2][24][4];

    const int t = threadIdx.x;
    if (t < 48) {
        const int row = t / 24;
        const int i   = t % 24;          // h*4+p
        const int h = i >> 2, p = i & 3;
        const int r = r0 + row;
        const float* oa = offaw + ((long long)m * RTOT + r) * 128;
        float e = oa[48 + h * 4 + p];
        float mx = fmaxf(e, __shfl_xor(e, 1));
        mx = fmaxf(mx, __shfl_xor(mx, 2));
        float ex = expf(e - mx);
        float s = ex;
        s += __shfl_xor(s, 1);
        s += __shfl_xor(s, 2);
        const float aw = ex / s;
        const float x = ref[r * 2 + 0] * 64.f - 0.5f + oa[h * 8 + p * 2 + 0];
        const float y = ref[r * 2 + 1] * 64.f - 0.5f + oa[h * 8 + p * 2 + 1];
        const float xf = floorf(x), yf = floorf(y);
        const float wx = x - xf, wy = y - yf;
        const int x0 = (int)xf, y0 = (int)yf;
        const bool xok0 = (x0 >= 0) && (x0 < 64);
        const bool xok1 = (x0 >= -1) && (x0 < 63);
        const bool yok0 = (y0 >= 0) && (y0 < 64);
        const bool yok1 = (y0 >= -1) && (y0 < 63);
        const int xc0 = min(max(x0, 0), 63),     xc1 = min(max(x0 + 1, 0), 63);
        const int yc0 = min(max(y0, 0), 63),     yc1 = min(max(y0 + 1, 0), 63);
        WP w0 = { aw * (1.f - wx) * (1.f - wy) * (float)(xok0 && yok0), (yc0 * 64 + xc0) * (C_ * 2) };
        WP w1 = { aw * wx         * (1.f - wy) * (float)(xok1 && yok0), (yc0 * 64 + xc1) * (C_ * 2) };
        WP w2 = { aw * (1.f - wx) * wy         * (float)(xok0 && yok1), (yc1 * 64 + xc0) * (C_ * 2) };
        WP w3 = { aw * wx         * wy         * (float)(xok1 && yok1), (yc1 * 64 + xc1) * (C_ * 2) };
        wp_s[row][i][0] = w0;  wp_s[row][i][1] = w1;
        wp_s[row][i][2] = w2;  wp_s[row][i][3] = w3;
    }
    __syncthreads();

    const int row = t / 192;             // 0..1
    const int tl  = t % 192;
    const int h   = tl >> 5;             // 0..5
    const int l32 = tl & 31;             // channel pair
    const int r   = r0 + row;
    const char* vb = (const char*)(value
        + ((long long)m * RTOT + (long long)b * 4096) * C_ + h * 64 + l32 * 2);

    float wreg[16]; int oreg[16]; unsigned int vreg[16];
#pragma unroll
    for (int i = 0; i < 16; ++i) {
        WP wp = wp_s[row][h * 4 + (i >> 2)][i & 3];
        wreg[i] = wp.w; oreg[i] = wp.off;
    }
#pragma unroll
    for (int i = 0; i < 16; ++i)
        vreg[i] = *reinterpret_cast<const unsigned int*>(vb + oreg[i]);
    float acc0 = 0.f, acc1 = 0.f;
#pragma unroll
    for (int i = 0; i < 16; ++i) {
        unsigned int u = vreg[i];
        float lo = __builtin_bit_cast(float, u << 16);
        float hi = __builtin_bit_cast(float, u & 0xffff0000u);
        acc0 += wreg[i] * lo;
        acc1 += wreg[i] * hi;
    }
    union { bf16 h2[2]; unsigned int u; } o;
    o.h2[0] = (bf16)acc0; o.h2[1] = (bf16)acc1;
    *reinterpret_cast<unsigned int*>(attn + (long long)r * KOUT + m * C_ + h * 64 + l32 * 2) = o.u;
}

// ---------------------------------------------------------------------------
extern "C" void kernel_launch(void* const* d_in, const int* in_sizes, int n_in,
                              void* d_out, int out_size, void* d_ws, size_t ws_size,
                              hipStream_t stream)
{
    const float* query      = (const float*)d_in[0];
    const float* ref        = (const float*)d_in[1];
    const float* feat       = (const float*)d_in[2];
    const float* feat_other = (const float*)d_in[3];
    const float* qn_g = (const float*)d_in[4];
    const float* qn_b = (const float*)d_in[5];
    const float* fn_g = (const float*)d_in[6];
    const float* fn_b = (const float*)d_in[7];
    const float* Wv   = (const float*)d_in[8];
    const float* bv   = (const float*)d_in[9];
    const float* Woff = (const float*)d_in[10];
    const float* boff = (const float*)d_in[11];
    const float* Waw  = (const float*)d_in[12];
    const float* baw  = (const float*)d_in[13];
    const float* Wout = (const float*)d_in[14];
    const float* bout = (const float*)d_in[15];
    const float* gamma = (const float*)d_in[16];
    float* out = (float*)d_out;

    char* ws = (char*)d_ws;
    size_t off = 0;
    auto carve = [&](size_t bytes) { char* p = ws + off; off += (bytes + 255) & ~(size_t)255; return p; };
    bf16*  qn      = (bf16*)carve((size_t)RTOT * C_ * 2);
    bf16*  fn      = (bf16*)carve((size_t)M_ * RTOT * C_ * 2);
    bf16*  value   = (bf16*)carve((size_t)M_ * RTOT * C_ * 2);
    bf16*  attn    = (bf16*)carve((size_t)RTOT * KOUT * 2);
    float* offaw   = (float*)carve((size_t)M_ * RTOT * 128 * 4);
    bf16*  WvT     = (bf16*)carve((size_t)M_ * C_ * C_ * 2);
    bf16*  WoffawT = (bf16*)carve((size_t)M_ * 128 * C_ * 2);
    bf16*  WoutT   = (bf16*)carve((size_t)C_ * KOUT * 2);
    float* oabias  = (float*)carve((size_t)M_ * 128 * 4);
    float* boutbig = (float*)carve((size_t)C_ * 4);

    cvt_kernel<<<512, 256, 0, stream>>>(Wv, Woff, Waw, Wout, gamma, boff, baw, bout,
                                        WvT, WoffawT, WoutT, oabias, boutbig);
    ln_kernel<<<dim3(RTOT / 4, 5), 256, 0, stream>>>(query, feat, feat_other,
                                                     qn_g, qn_b, fn_g, fn_b, qn, fn);
    // value[m] = fn[m] @ WvT[m] + bv[m]   (bf16 out)
    gemm_kernel<0><<<dim3(RTOT / 64, C_ / 64, M_), 256, 0, stream>>>(
        fn, (long long)RTOT * C_, WvT, (long long)C_ * C_, bv, C_, nullptr,
        value, (long long)RTOT * C_, C_, C_);
    // offaw[m] = qn @ WoffawT[m] + oabias  (f32 out, N=128)
    gemm_kernel<1><<<dim3(RTOT / 64, 2, M_), 256, 0, stream>>>(
        qn, 0LL, WoffawT, (long long)128 * C_, oabias, 128, nullptr,
        offaw, (long long)RTOT * 128, C_, 128);
    // sampling -> attn [R][1536] bf16
    sample_kernel<<<dim3(RTOT * M_ / 2), 384, 0, stream>>>(offaw, ref, value, attn);
    // out = query + attn @ WoutT + boutbig  (K=1536)
    gemm_kernel<2><<<dim3(RTOT / 64, C_ / 64, 1), 256, 0, stream>>>(
        attn, 0LL, WoutT, 0LL, boutbig, 0, query,
        out, 0LL, KOUT, C_);
}